// Round 18
// baseline (197.958 us; speedup 1.0000x reference)
//
#include <hip/hip_runtime.h>
#include <stdint.h>
#include <math.h>

#define HW_ 16384   // H*W = 128*128
#define C_  256
#define NT  4       // tiles per block (each tile = 128 positions)

typedef long i64;
typedef float f32x4 __attribute__((ext_vector_type(4)));
typedef unsigned int u32;

// barrier WITHOUT vmcnt drain: orders LDS only; prefetch loads stay in flight
#define BARRIER_LGKM() asm volatile("s_waitcnt lgkmcnt(0)\n\ts_barrier" ::: "memory")

// -------- kernel 0: prep (W -> fp8 e4m3 in MFMA-fragment order, BN consts) --
// Wp byte layout: idx = ((ks*16 + mf)*64 + kg*16 + r15)*8 + e
__global__ __launch_bounds__(256) void k0_prep(
    const float* __restrict__ w_fe, const float* __restrict__ gamma,
    const float* __restrict__ beta, const float* __restrict__ mean,
    const float* __restrict__ var, u32* __restrict__ Wp,
    float* __restrict__ scale, float* __restrict__ shift)
{
  int i = blockIdx.x * 256 + threadIdx.x;
  if (i < 32768) {                     // one u32 = 4 fp8 bytes
    int e0  = (i & 1) * 4;
    int r15 = (i >> 1) & 15;
    int kg  = (i >> 5) & 3;
    int mf  = (i >> 7) & 15;
    int ks  = i >> 11;
    int row = mf * 16 + r15;
    int k   = ks * 32 + kg * 8 + e0;   // 4 consecutive k
    const float* src = w_fe + row * 512 + k;
    u32 w = 0;
    w = __builtin_amdgcn_cvt_pk_fp8_f32(src[0], src[1], w, false);
    w = __builtin_amdgcn_cvt_pk_fp8_f32(src[2], src[3], w, true);
    Wp[i] = w;
  }
  if (i < 256) {
    float sc = gamma[i] * rsqrtf(var[i] + 1e-5f);
    scale[i] = sc;
    shift[i] = beta[i] - mean[i] * sc;
  }
}

// ------- kernel q8: streaming quantize X -> X8 (fp8, row-major) -------
// X8 layout: [b][512 rows][16384 pos]; rows 0-255 = x1 ch, 256-511 = x2 ch.
// COALESCED: per wave-instruction, 64 lanes x float4 = 1 KB contiguous read
// (m13 pattern); stores 64 x u32 = 256 B contiguous. Block = quarter-row.
__global__ __launch_bounds__(256) void kq8(
    const float* __restrict__ x1, const float* __restrict__ x2,
    u32* __restrict__ X8)
{
  const int blk = blockIdx.x;           // 16384 blocks
  const int R   = blk >> 2;             // global row 0..4095
  const int b   = R >> 9;
  const int r   = R & 511;
  const int base = (blk & 3) * 4096;    // float offset within the row
  const float* src = ((r < 256) ? (x1 + ((size_t)(b * 256 + r) << 14))
                                : (x2 + ((size_t)(b * 256 + r - 256) << 14)))
                     + base;
  u32* dst = (u32*)((char*)X8 + ((size_t)R << 14) + base);  // 1 B per float
#pragma unroll
  for (int it = 0; it < 4; ++it) {
    const int off = it * 1024 + threadIdx.x * 4;   // float offset
    f32x4 v = *(const f32x4*)(src + off);
    u32 o = __builtin_amdgcn_cvt_pk_fp8_f32(v[0], v[1], 0u, false);
    o     = __builtin_amdgcn_cvt_pk_fp8_f32(v[2], v[3], o, true);
    dst[off >> 2] = o;
  }
}

// ------- kernel 1q: fp8-gather MFMA GEMM + BN + ReLU + pool -------
// R12's structure/LDS algebra; gather reads fp8 X8 (67MB -- 4x fewer bytes
// through the byte-rate-capped strided path). Validated in R17.
__global__ __launch_bounds__(1024, 4) void k1q(
    const char* __restrict__ X8, const u32* __restrict__ Wp,
    const float* __restrict__ scale, const float* __restrict__ shift,
    float* __restrict__ pool_part)
{
  __shared__ __align__(16) char Bl[2][65536];   // 2 x 64KB

  const int tid  = threadIdx.x;
  const int wave = tid >> 6;        // = mf
  const int lane = tid & 63;
  const int r15  = lane & 15;
  const int kg   = lane >> 4;
  const int blk  = blockIdx.x;
  const int b    = blk >> 5;                 // batch
  const int t0   = (blk & 31) * NT;

  const char* Xb = X8 + ((size_t)b << 23);   // this batch's 512 rows

  const int o   = tid >> 5;          // 0..31 octet within half
  const int q   = tid & 31;          // pos-quad
  const int pq  = q * 4;             // pos base 0..124
  const int wq  = (q * 32) ^ ((o & 3) << 5);
  const int rb_off = (r15 * 8) ^ (kg << 5);

  // ---- A-frags once for this wave (16 x i64 = 32 regs) ----
  i64 Af[16];
#pragma unroll
  for (int ks = 0; ks < 16; ++ks)
    Af[ks] = *(const i64*)((const char*)Wp
             + ((ks * 16 + wave) * 64 + kg * 16 + r15) * 8);

  const int chbase = wave * 16 + kg * 4;
  const float4 sc4 = *(const float4*)&scale[chbase];
  const float4 sh4 = *(const float4*)&shift[chbase];

  float pool0 = 0.f, pool1 = 0.f, pool2 = 0.f, pool3 = 0.f;

  u32 gq[4];   // staging sub-unit: 4 rows x 4 pos (4 regs)

#define ISSUE_U(H, S, P0)                                                     \
  {                                                                           \
    const char* s0 = Xb + (((size_t)((H) * 256 + o * 8 + (S) * 4)) << 14)     \
                     + (P0) + pq;                                             \
    _Pragma("unroll")                                                         \
    for (int r = 0; r < 4; ++r) gq[r] = *(const u32*)(s0 + ((size_t)r << 14));\
  }

#define WRITE_U(H, S, BUF)                                                    \
  {                                                                           \
    char* wb = (char*)(BUF) + ((H) * 32 + o) * 1024 + wq + (S) * 4;           \
    _Pragma("unroll")                                                         \
    for (int j = 0; j < 4; ++j) {                                             \
      u32 w = ((gq[0] >> (8 * j)) & 0xffu)                                    \
            | (((gq[1] >> (8 * j)) & 0xffu) << 8)                             \
            | (((gq[2] >> (8 * j)) & 0xffu) << 16)                            \
            | (((gq[3] >> (8 * j)) & 0xffu) << 24);                           \
      *(u32*)(wb + j * 8) = w;                                                \
    }                                                                         \
  }

#define COMPUTE_Q(QK, BUF)                                                    \
  {                                                                           \
    _Pragma("unroll")                                                         \
    for (int ks = (QK) * 4; ks < (QK) * 4 + 4; ++ks) {                        \
      const char* rb = (const char*)(BUF) + (ks * 4 + kg) * 1024 + rb_off;    \
      _Pragma("unroll")                                                       \
      for (int nf = 0; nf < 8; ++nf) {                                        \
        i64 bq = *(const i64*)(rb + nf * 128);                                \
        acc[nf] = __builtin_amdgcn_mfma_f32_16x16x32_fp8_fp8(                 \
            Af[ks], bq, acc[nf], 0, 0, 0);                                    \
      }                                                                       \
    }                                                                         \
  }

  ISSUE_U(0, 0, t0 * 128) WRITE_U(0, 0, Bl[0])
  ISSUE_U(0, 1, t0 * 128) WRITE_U(0, 1, Bl[0])
  ISSUE_U(1, 0, t0 * 128) WRITE_U(1, 0, Bl[0])
  ISSUE_U(1, 1, t0 * 128) WRITE_U(1, 1, Bl[0])
  __syncthreads();

  for (int tt = 0; tt < NT; ++tt) {
    f32x4 acc[8];
#pragma unroll
    for (int nf = 0; nf < 8; ++nf) acc[nf] = (f32x4){0.f, 0.f, 0.f, 0.f};

    const int p1 = (t0 + tt + 1) * 128;
    const bool more = (tt + 1 < NT);
    const char* cb = Bl[tt & 1];
    char* nxt = Bl[(tt + 1) & 1];

    if (more) ISSUE_U(0, 0, p1)
    COMPUTE_Q(0, cb)
    if (more) { WRITE_U(0, 0, nxt) ISSUE_U(0, 1, p1) }
    COMPUTE_Q(1, cb)
    if (more) { WRITE_U(0, 1, nxt) ISSUE_U(1, 0, p1) }
    COMPUTE_Q(2, cb)
    if (more) { WRITE_U(1, 0, nxt) ISSUE_U(1, 1, p1) }
    COMPUTE_Q(3, cb)
    if (more) WRITE_U(1, 1, nxt)

#pragma unroll
    for (int nf = 0; nf < 8; ++nf) {
      pool0 += fmaxf(acc[nf][0] * sc4.x + sh4.x, 0.f);
      pool1 += fmaxf(acc[nf][1] * sc4.y + sh4.y, 0.f);
      pool2 += fmaxf(acc[nf][2] * sc4.z + sh4.z, 0.f);
      pool3 += fmaxf(acc[nf][3] * sc4.w + sh4.w, 0.f);
    }
    BARRIER_LGKM();
  }

#pragma unroll
  for (int m = 1; m < 16; m <<= 1) {
    pool0 += __shfl_xor(pool0, m);
    pool1 += __shfl_xor(pool1, m);
    pool2 += __shfl_xor(pool2, m);
    pool3 += __shfl_xor(pool3, m);
  }
  if (r15 == 0) {
    float* dst = pool_part + (size_t)blk * 256 + chbase;
    dst[0] = pool0; dst[1] = pool1; dst[2] = pool2; dst[3] = pool3;
  }
}

// ------- kernel 1 FALLBACK: R12 k1 verbatim (f32 gather) -------
__global__ __launch_bounds__(1024, 4) void k1_fb(
    const float* __restrict__ x1, const float* __restrict__ x2,
    const u32* __restrict__ Wp,
    const float* __restrict__ scale, const float* __restrict__ shift,
    float* __restrict__ pool_part)
{
  __shared__ __align__(16) char Bl[2][65536];
  const int tid  = threadIdx.x;
  const int wave = tid >> 6;
  const int lane = tid & 63;
  const int r15  = lane & 15;
  const int kg   = lane >> 4;
  const int blk  = blockIdx.x;
  const int b    = blk >> 5;
  const int t0   = (blk & 31) * NT;
  const float* xb1 = x1 + (size_t)b * C_ * HW_;
  const float* xb2 = x2 + (size_t)b * C_ * HW_;
  const int o   = tid >> 5;
  const int q   = tid & 31;
  const int pq  = q * 4;
  const int wq  = (q * 32) ^ ((o & 3) << 5);
  const int rb_off = (r15 * 8) ^ (kg << 5);
  i64 Af[16];
#pragma unroll
  for (int ks = 0; ks < 16; ++ks)
    Af[ks] = *(const i64*)((const char*)Wp
             + ((ks * 16 + wave) * 64 + kg * 16 + r15) * 8);
  const int chbase = wave * 16 + kg * 4;
  const float4 sc4 = *(const float4*)&scale[chbase];
  const float4 sh4 = *(const float4*)&shift[chbase];
  float pool0 = 0.f, pool1 = 0.f, pool2 = 0.f, pool3 = 0.f;
  f32x4 gU[4];
#define FISSUE(H, S, P0)                                                      \
  { const float* s0 = ((H) == 0 ? xb1 : xb2)                                  \
                      + (size_t)(o * 8 + (S) * 4) * HW_ + (P0) + pq;          \
    _Pragma("unroll")                                                         \
    for (int r = 0; r < 4; ++r) gU[r] = *(const f32x4*)(s0 + r * HW_); }
#define FWRITE(H, S, BUF)                                                     \
  { char* wb = (char*)(BUF) + ((H) * 32 + o) * 1024 + wq + (S) * 4;           \
    _Pragma("unroll")                                                         \
    for (int j = 0; j < 4; ++j) {                                             \
      u32 w = 0;                                                              \
      w = __builtin_amdgcn_cvt_pk_fp8_f32(gU[0][j], gU[1][j], w, false);      \
      w = __builtin_amdgcn_cvt_pk_fp8_f32(gU[2][j], gU[3][j], w, true);       \
      *(u32*)(wb + j * 8) = w; } }
#define FCOMP(QK, BUF)                                                        \
  { _Pragma("unroll")                                                         \
    for (int ks = (QK) * 4; ks < (QK) * 4 + 4; ++ks) {                        \
      const char* rb = (const char*)(BUF) + (ks * 4 + kg) * 1024 + rb_off;    \
      _Pragma("unroll")                                                       \
      for (int nf = 0; nf < 8; ++nf) {                                        \
        i64 bq = *(const i64*)(rb + nf * 128);                                \
        acc[nf] = __builtin_amdgcn_mfma_f32_16x16x32_fp8_fp8(                 \
            Af[ks], bq, acc[nf], 0, 0, 0); } } }
  FISSUE(0, 0, t0 * 128) FWRITE(0, 0, Bl[0])
  FISSUE(0, 1, t0 * 128) FWRITE(0, 1, Bl[0])
  FISSUE(1, 0, t0 * 128) FWRITE(1, 0, Bl[0])
  FISSUE(1, 1, t0 * 128) FWRITE(1, 1, Bl[0])
  __syncthreads();
  for (int tt = 0; tt < NT; ++tt) {
    f32x4 acc[8];
#pragma unroll
    for (int nf = 0; nf < 8; ++nf) acc[nf] = (f32x4){0.f, 0.f, 0.f, 0.f};
    const int p1 = (t0 + tt + 1) * 128;
    const bool more = (tt + 1 < NT);
    const char* cb = Bl[tt & 1];
    char* nxt = Bl[(tt + 1) & 1];
    if (more) FISSUE(0, 0, p1)
    FCOMP(0, cb)
    if (more) { FWRITE(0, 0, nxt) FISSUE(0, 1, p1) }
    FCOMP(1, cb)
    if (more) { FWRITE(0, 1, nxt) FISSUE(1, 0, p1) }
    FCOMP(2, cb)
    if (more) { FWRITE(1, 0, nxt) FISSUE(1, 1, p1) }
    FCOMP(3, cb)
    if (more) FWRITE(1, 1, nxt)
#pragma unroll
    for (int nf = 0; nf < 8; ++nf) {
      pool0 += fmaxf(acc[nf][0] * sc4.x + sh4.x, 0.f);
      pool1 += fmaxf(acc[nf][1] * sc4.y + sh4.y, 0.f);
      pool2 += fmaxf(acc[nf][2] * sc4.z + sh4.z, 0.f);
      pool3 += fmaxf(acc[nf][3] * sc4.w + sh4.w, 0.f);
    }
    BARRIER_LGKM();
  }
#pragma unroll
  for (int m = 1; m < 16; m <<= 1) {
    pool0 += __shfl_xor(pool0, m);
    pool1 += __shfl_xor(pool1, m);
    pool2 += __shfl_xor(pool2, m);
    pool3 += __shfl_xor(pool3, m);
  }
  if (r15 == 0) {
    float* dst = pool_part + (size_t)blk * 256 + chbase;
    dst[0] = pool0; dst[1] = pool1; dst[2] = pool2; dst[3] = pool3;
  }
}

// -------- kernel 2: tiny MLPs -> per-(b,c) 3x3 kernels + attn coefs --------
__global__ __launch_bounds__(256) void k2_small(
    const float* __restrict__ pool_part,
    const float* __restrict__ w_cg1, const float* __restrict__ w_cg2,
    const float* __restrict__ w_ag1, const float* __restrict__ w_ag2,
    float* __restrict__ cw, float* __restrict__ coef)
{
  __shared__ float pl[256];
  __shared__ float hl[64];
  const int bi = blockIdx.x;
  const int b = bi / 10, j = bi % 10;
  const int t = threadIdx.x;
  float s = 0.f;
  const float* base = pool_part + (size_t)b * 32 * 256 + t;
  for (int blk = 0; blk < 32; ++blk) s += base[blk * 256];   // fixed order
  pl[t] = s * (1.0f / 16384.0f);
  __syncthreads();
  if (j < 9) {
    if (t < 64) {
      float h = 0.f;
      for (int i = 0; i < 256; ++i) h += pl[i] * w_cg1[t * 256 + i];
      hl[t] = fmaxf(h, 0.f);
    }
    __syncthreads();
    const int o = t * 9 + j;
    float acc = 0.f;
    for (int jj = 0; jj < 64; ++jj) acc += hl[jj] * w_cg2[o * 64 + jj];
    cw[b * 2304 + o] = acc;
  } else {
    if (t < 64) {
      float a = 0.f;
      for (int i = 0; i < 256; ++i) a += pl[i] * w_ag1[t * 256 + i];
      hl[t] = fmaxf(a, 0.f);
    }
    __syncthreads();
    if (t < 2) {
      float acc = 0.f;
      for (int jj = 0; jj < 64; ++jj) acc += hl[jj] * w_ag2[t * 64 + jj];
      coef[b * 2 + t] = 0.25f / (1.0f + expf(-acc));   // 0.25 = L_S * L_C
    }
  }
}

// -------- kernel 3: depthwise 3x3 (same kernel on x1 & x2) + combine --------
__global__ __launch_bounds__(256) void k3_dynconv(
    const float* __restrict__ x1, const float* __restrict__ x2,
    const float* __restrict__ cw, const float* __restrict__ coef,
    float* __restrict__ out)
{
  __shared__ float t1[34 * 128];
  __shared__ float t2[34 * 128];
  const int tid   = threadIdx.x;
  const int blk   = blockIdx.x;
  const int strip = blk & 3;
  const int c     = (blk >> 2) & 255;
  const int b     = blk >> 10;
  const int h0    = strip * 32;

  const size_t plane = ((size_t)b * C_ + c) * HW_;
  const float* p1 = x1 + plane;
  const float* p2 = x2 + plane;

  float tp[9];
#pragma unroll
  for (int e = 0; e < 9; ++e) tp[e] = cw[(b * C_ + c) * 9 + e];
  const float c1 = coef[b * 2 + 0];
  const float c2 = coef[b * 2 + 1];

  for (int f = tid; f < 1088; f += 256) {
    int row = f >> 5;
    int c4  = (f & 31) << 2;
    int gh  = h0 - 1 + row;
    float4 v1 = make_float4(0.f, 0.f, 0.f, 0.f), v2 = v1;
    if (gh >= 0 && gh < 128) {
      v1 = *(const float4*)&p1[gh * 128 + c4];
      v2 = *(const float4*)&p2[gh * 128 + c4];
    }
    *(float4*)&t1[row * 128 + c4] = v1;
    *(float4*)&t2[row * 128 + c4] = v2;
  }
  __syncthreads();

  for (int i = 0; i < 16; ++i) {
    int q   = tid + i * 256;
    int r   = q >> 7;
    int col = q & 127;
    int lr  = r + 1;
    const bool lok = col > 0, rok = col < 127;
    float d1 = 0.f, d2 = 0.f;
#pragma unroll
    for (int dy = 0; dy < 3; ++dy) {
      const float* row1 = &t1[(lr - 1 + dy) * 128];
      const float* row2 = &t2[(lr - 1 + dy) * 128];
      float a1v = lok ? row1[col - 1] : 0.f;
      float b1v = row1[col];
      float e1v = rok ? row1[col + 1] : 0.f;
      float a2v = lok ? row2[col - 1] : 0.f;
      float b2v = row2[col];
      float e2v = rok ? row2[col + 1] : 0.f;
      d1 += a1v * tp[dy * 3 + 0] + b1v * tp[dy * 3 + 1] + e1v * tp[dy * 3 + 2];
      d2 += a2v * tp[dy * 3 + 0] + b2v * tp[dy * 3 + 1] + e2v * tp[dy * 3 + 2];
    }
    float v1 = t1[lr * 128 + col];
    float v2 = t2[lr * 128 + col];
    out[plane + (size_t)(h0 + r) * 128 + col] = 0.5f * (v1 + v2) + c1 * d1 + c2 * d2;
  }
}

extern "C" void kernel_launch(void* const* d_in, const int* in_sizes, int n_in,
                              void* d_out, int out_size, void* d_ws, size_t ws_size,
                              hipStream_t stream) {
  const float* x1    = (const float*)d_in[0];
  const float* x2    = (const float*)d_in[1];
  const float* w_fe  = (const float*)d_in[2];
  const float* gamma = (const float*)d_in[3];
  const float* beta  = (const float*)d_in[4];
  const float* mean  = (const float*)d_in[5];
  const float* var   = (const float*)d_in[6];
  const float* w_cg1 = (const float*)d_in[7];
  const float* w_cg2 = (const float*)d_in[8];
  const float* w_ag1 = (const float*)d_in[9];
  const float* w_ag2 = (const float*)d_in[10];
  float* out = (float*)d_out;

  char* ws = (char*)d_ws;
  u32* Wp          = (u32*)(ws);                           // [0, 131072)
  float* scale     = (float*)(ws + 131072);                // 1 KB
  float* shift     = (float*)(ws + 132096);                // 1 KB
  float* pool_part = (float*)(ws + 133120);                // 256 KB
  float* cw        = (float*)(ws + 395264);                // 73728 B
  float* coef      = (float*)(ws + 468992);                // 64 B
  char* X8         = ws + 524288;                          // 67,108,864 B
  const size_t NEED = 524288 + (size_t)8 * 512 * 16384;    // 67,633,152

  k0_prep<<<128, 256, 0, stream>>>(w_fe, gamma, beta, mean, var, Wp, scale, shift);
  if (ws_size >= NEED) {
    kq8<<<16384, 256, 0, stream>>>(x1, x2, (u32*)X8);
    k1q<<<256, 1024, 0, stream>>>(X8, Wp, scale, shift, pool_part);
  } else {
    k1_fb<<<256, 1024, 0, stream>>>(x1, x2, Wp, scale, shift, pool_part);
  }
  k2_small<<<80, 256, 0, stream>>>(pool_part, w_cg1, w_cg2, w_ag1, w_ag2, cw, coef);
  k3_dynconv<<<8192, 256, 0, stream>>>(x1, x2, cw, coef, out);
}

// Round 19
// 152.667 us; speedup vs baseline: 1.2967x; 1.2967x over previous
//
#include <hip/hip_runtime.h>
#include <stdint.h>
#include <math.h>

#define HW_ 16384   // H*W = 128*128
#define C_  256
#define NT  4       // tiles per block (each tile = 128 positions)

typedef long i64;
typedef float f32x4 __attribute__((ext_vector_type(4)));
typedef unsigned int u32;

// barrier WITHOUT vmcnt drain: orders LDS only; prefetch loads stay in flight
#define BARRIER_LGKM() asm volatile("s_waitcnt lgkmcnt(0)\n\ts_barrier" ::: "memory")

// -------- kernel 0: prep (W -> fp8 e4m3 in MFMA-fragment order, BN consts) --
// Wp byte layout: idx = ((ks*16 + mf)*64 + kg*16 + r15)*8 + e
__global__ __launch_bounds__(256) void k0_prep(
    const float* __restrict__ w_fe, const float* __restrict__ gamma,
    const float* __restrict__ beta, const float* __restrict__ mean,
    const float* __restrict__ var, u32* __restrict__ Wp,
    float* __restrict__ scale, float* __restrict__ shift)
{
  int i = blockIdx.x * 256 + threadIdx.x;
  if (i < 32768) {                     // one u32 = 4 fp8 bytes
    int e0  = (i & 1) * 4;
    int r15 = (i >> 1) & 15;
    int kg  = (i >> 5) & 3;
    int mf  = (i >> 7) & 15;
    int ks  = i >> 11;
    int row = mf * 16 + r15;
    int k   = ks * 32 + kg * 8 + e0;   // 4 consecutive k
    const float* src = w_fe + row * 512 + k;
    u32 w = 0;
    w = __builtin_amdgcn_cvt_pk_fp8_f32(src[0], src[1], w, false);
    w = __builtin_amdgcn_cvt_pk_fp8_f32(src[2], src[3], w, true);
    Wp[i] = w;
  }
  if (i < 256) {
    float sc = gamma[i] * rsqrtf(var[i] + 1e-5f);
    scale[i] = sc;
    shift[i] = beta[i] - mean[i] * sc;
  }
}

// ------- kernel 1: persistent-W fp8 MFMA GEMM + BN + ReLU + pool -------
// 16 waves; wave w = m-frag w. A-frags (fp8, 32 regs) persistent. Tile = 128
// pos x 512 k fp8 in LDS, layout [K-octet 0..63][p 0..127][e 0..7] with XOR
// swizzle (p*8 ^ (K&3)<<5): b64 frag reads 4-way, b32 stage writes 8-way.
// Staging: 4x float4 per sub-unit (16 live regs, no spill). Double-buffered,
// lgkm-only barrier (loads stay in flight). Grid: 256 x 1024.
// This is the measured optimum (R12: k1 ~107 us, total 152.3 us). The ~2.5
// TB/s gather-delivery cap proved invariant across 15 structural variants
// (R5-R18); see session ledger.
__global__ __launch_bounds__(1024, 4) void k1_gemm_pool(
    const float* __restrict__ x1, const float* __restrict__ x2,
    const u32* __restrict__ Wp,
    const float* __restrict__ scale, const float* __restrict__ shift,
    float* __restrict__ pool_part)
{
  __shared__ __align__(16) char Bl[2][65536];   // 2 x 64KB

  const int tid  = threadIdx.x;
  const int wave = tid >> 6;        // = mf
  const int lane = tid & 63;
  const int r15  = lane & 15;
  const int kg   = lane >> 4;
  const int blk  = blockIdx.x;
  const int b    = blk >> 5;                 // batch
  const int t0   = (blk & 31) * NT;

  const float* xb1 = x1 + (size_t)b * C_ * HW_;
  const float* xb2 = x2 + (size_t)b * C_ * HW_;

  // staging decomposition: thread owns (octet o, pos-quad q) per k-half
  const int o   = tid >> 5;          // 0..31 octet within half
  const int q   = tid & 31;          // pos-quad
  const int pq  = q * 4;             // pos base 0..124
  const int wq  = (q * 32) ^ ((o & 3) << 5);   // swizzled pos-part of write addr

  // frag-read constant: swizzled lane offset within an octet block
  const int rb_off = (r15 * 8) ^ (kg << 5);

  // ---- A-frags once for this wave (16 x i64 = 32 regs) ----
  i64 Af[16];
#pragma unroll
  for (int ks = 0; ks < 16; ++ks)
    Af[ks] = *(const i64*)((const char*)Wp
             + ((ks * 16 + wave) * 64 + kg * 16 + r15) * 8);

  const int chbase = wave * 16 + kg * 4;
  const float4 sc4 = *(const float4*)&scale[chbase];
  const float4 sh4 = *(const float4*)&shift[chbase];

  float pool0 = 0.f, pool1 = 0.f, pool2 = 0.f, pool3 = 0.f;

  f32x4 gU[4];   // staging sub-unit: 4 rows x 4 pos (16 regs live)

// Load sub-unit (H half, S row-group) of tile at base pos P0.
#define ISSUE_U(H, S, P0)                                                     \
  {                                                                           \
    const float* s0 = ((H) == 0 ? xb1 : xb2)                                  \
                      + (size_t)(o * 8 + (S) * 4) * HW_ + (P0) + pq;          \
    _Pragma("unroll")                                                         \
    for (int r = 0; r < 4; ++r) gU[r] = *(const f32x4*)(s0 + r * HW_);        \
  }

// Convert sub-unit to fp8, write 4 x b32 (w-half S of 4 positions).
#define WRITE_U(H, S, BUF)                                                    \
  {                                                                           \
    char* wb = (char*)(BUF) + ((H) * 32 + o) * 1024 + wq + (S) * 4;           \
    _Pragma("unroll")                                                         \
    for (int j = 0; j < 4; ++j) {                                             \
      u32 w = 0;                                                              \
      w = __builtin_amdgcn_cvt_pk_fp8_f32(gU[0][j], gU[1][j], w, false);      \
      w = __builtin_amdgcn_cvt_pk_fp8_f32(gU[2][j], gU[3][j], w, true);       \
      *(u32*)(wb + j * 8) = w;                                                \
    }                                                                         \
  }

// Quarter-compute: 4 ks x 8 nf = 32 b64 reads + 32 MFMA.
#define COMPUTE_Q(QK, BUF)                                                    \
  {                                                                           \
    _Pragma("unroll")                                                         \
    for (int ks = (QK) * 4; ks < (QK) * 4 + 4; ++ks) {                        \
      const char* rb = (const char*)(BUF) + (ks * 4 + kg) * 1024 + rb_off;    \
      _Pragma("unroll")                                                       \
      for (int nf = 0; nf < 8; ++nf) {                                        \
        i64 bq = *(const i64*)(rb + nf * 128);                                \
        acc[nf] = __builtin_amdgcn_mfma_f32_16x16x32_fp8_fp8(                 \
            Af[ks], bq, acc[nf], 0, 0, 0);                                    \
      }                                                                       \
    }                                                                         \
  }

  // ---- prologue: stage tile t0 into buf 0 ----
  ISSUE_U(0, 0, t0 * 128) WRITE_U(0, 0, Bl[0])
  ISSUE_U(0, 1, t0 * 128) WRITE_U(0, 1, Bl[0])
  ISSUE_U(1, 0, t0 * 128) WRITE_U(1, 0, Bl[0])
  ISSUE_U(1, 1, t0 * 128) WRITE_U(1, 1, Bl[0])
  __syncthreads();

  for (int tt = 0; tt < NT; ++tt) {
    f32x4 acc[8];
#pragma unroll
    for (int nf = 0; nf < 8; ++nf) acc[nf] = (f32x4){0.f, 0.f, 0.f, 0.f};

    const int p1 = (t0 + tt + 1) * 128;
    const bool more = (tt + 1 < NT);
    const char* cb = Bl[tt & 1];
    char* nxt = Bl[(tt + 1) & 1];

    if (more) ISSUE_U(0, 0, p1)
    COMPUTE_Q(0, cb)
    if (more) { WRITE_U(0, 0, nxt) ISSUE_U(0, 1, p1) }
    COMPUTE_Q(1, cb)
    if (more) { WRITE_U(0, 1, nxt) ISSUE_U(1, 0, p1) }
    COMPUTE_Q(2, cb)
    if (more) { WRITE_U(1, 0, nxt) ISSUE_U(1, 1, p1) }
    COMPUTE_Q(3, cb)
    if (more) WRITE_U(1, 1, nxt)

    // pool accumulate: BN + ReLU over this tile's 128 positions
#pragma unroll
    for (int nf = 0; nf < 8; ++nf) {
      pool0 += fmaxf(acc[nf][0] * sc4.x + sh4.x, 0.f);
      pool1 += fmaxf(acc[nf][1] * sc4.y + sh4.y, 0.f);
      pool2 += fmaxf(acc[nf][2] * sc4.z + sh4.z, 0.f);
      pool3 += fmaxf(acc[nf][3] * sc4.w + sh4.w, 0.f);
    }
    BARRIER_LGKM();                    // loads stay in flight across barrier
  }

  // reduce over the 16 positions (r15 lanes)
#pragma unroll
  for (int m = 1; m < 16; m <<= 1) {
    pool0 += __shfl_xor(pool0, m);
    pool1 += __shfl_xor(pool1, m);
    pool2 += __shfl_xor(pool2, m);
    pool3 += __shfl_xor(pool3, m);
  }
  if (r15 == 0) {
    float* dst = pool_part + (size_t)blk * 256 + chbase;
    dst[0] = pool0; dst[1] = pool1; dst[2] = pool2; dst[3] = pool3;
  }
}

// -------- kernel 2: tiny MLPs -> per-(b,c) 3x3 kernels + attn coefs --------
// grid 80 = 8 batches x 10 jobs (j=0..8: tap j of all 256 channels; j=9: coef)
__global__ __launch_bounds__(256) void k2_small(
    const float* __restrict__ pool_part,
    const float* __restrict__ w_cg1, const float* __restrict__ w_cg2,
    const float* __restrict__ w_ag1, const float* __restrict__ w_ag2,
    float* __restrict__ cw, float* __restrict__ coef)
{
  __shared__ float pl[256];
  __shared__ float hl[64];
  const int bi = blockIdx.x;
  const int b = bi / 10, j = bi % 10;
  const int t = threadIdx.x;
  float s = 0.f;
  const float* base = pool_part + (size_t)b * 32 * 256 + t;
  for (int blk = 0; blk < 32; ++blk) s += base[blk * 256];   // fixed order
  pl[t] = s * (1.0f / 16384.0f);
  __syncthreads();
  if (j < 9) {
    if (t < 64) {
      float h = 0.f;
      for (int i = 0; i < 256; ++i) h += pl[i] * w_cg1[t * 256 + i];
      hl[t] = fmaxf(h, 0.f);
    }
    __syncthreads();
    const int o = t * 9 + j;                 // row of w_cg2 = c*9 + tap
    float acc = 0.f;
    for (int jj = 0; jj < 64; ++jj) acc += hl[jj] * w_cg2[o * 64 + jj];
    cw[b * 2304 + o] = acc;
  } else {
    if (t < 64) {
      float a = 0.f;
      for (int i = 0; i < 256; ++i) a += pl[i] * w_ag1[t * 256 + i];
      hl[t] = fmaxf(a, 0.f);
    }
    __syncthreads();
    if (t < 2) {
      float acc = 0.f;
      for (int jj = 0; jj < 64; ++jj) acc += hl[jj] * w_ag2[t * 64 + jj];
      coef[b * 2 + t] = 0.25f / (1.0f + expf(-acc));   // 0.25 = L_S * L_C
    }
  }
}

// -------- kernel 3: depthwise 3x3 (same kernel on x1 & x2) + combine --------
__global__ __launch_bounds__(256) void k3_dynconv(
    const float* __restrict__ x1, const float* __restrict__ x2,
    const float* __restrict__ cw, const float* __restrict__ coef,
    float* __restrict__ out)
{
  __shared__ float t1[34 * 128];
  __shared__ float t2[34 * 128];
  const int tid   = threadIdx.x;
  const int blk   = blockIdx.x;
  const int strip = blk & 3;
  const int c     = (blk >> 2) & 255;
  const int b     = blk >> 10;
  const int h0    = strip * 32;

  const size_t plane = ((size_t)b * C_ + c) * HW_;
  const float* p1 = x1 + plane;
  const float* p2 = x2 + plane;

  float tp[9];
#pragma unroll
  for (int e = 0; e < 9; ++e) tp[e] = cw[(b * C_ + c) * 9 + e];
  const float c1 = coef[b * 2 + 0];
  const float c2 = coef[b * 2 + 1];

  for (int f = tid; f < 1088; f += 256) {
    int row = f >> 5;
    int c4  = (f & 31) << 2;
    int gh  = h0 - 1 + row;
    float4 v1 = make_float4(0.f, 0.f, 0.f, 0.f), v2 = v1;
    if (gh >= 0 && gh < 128) {
      v1 = *(const float4*)&p1[gh * 128 + c4];
      v2 = *(const float4*)&p2[gh * 128 + c4];
    }
    *(float4*)&t1[row * 128 + c4] = v1;
    *(float4*)&t2[row * 128 + c4] = v2;
  }
  __syncthreads();

  for (int i = 0; i < 16; ++i) {
    int q   = tid + i * 256;
    int r   = q >> 7;
    int col = q & 127;
    int lr  = r + 1;
    const bool lok = col > 0, rok = col < 127;
    float d1 = 0.f, d2 = 0.f;
#pragma unroll
    for (int dy = 0; dy < 3; ++dy) {
      const float* row1 = &t1[(lr - 1 + dy) * 128];
      const float* row2 = &t2[(lr - 1 + dy) * 128];
      float a1v = lok ? row1[col - 1] : 0.f;
      float b1v = row1[col];
      float e1v = rok ? row1[col + 1] : 0.f;
      float a2v = lok ? row2[col - 1] : 0.f;
      float b2v = row2[col];
      float e2v = rok ? row2[col + 1] : 0.f;
      d1 += a1v * tp[dy * 3 + 0] + b1v * tp[dy * 3 + 1] + e1v * tp[dy * 3 + 2];
      d2 += a2v * tp[dy * 3 + 0] + b2v * tp[dy * 3 + 1] + e2v * tp[dy * 3 + 2];
    }
    float v1 = t1[lr * 128 + col];
    float v2 = t2[lr * 128 + col];
    out[plane + (size_t)(h0 + r) * 128 + col] = 0.5f * (v1 + v2) + c1 * d1 + c2 * d2;
  }
}

extern "C" void kernel_launch(void* const* d_in, const int* in_sizes, int n_in,
                              void* d_out, int out_size, void* d_ws, size_t ws_size,
                              hipStream_t stream) {
  const float* x1    = (const float*)d_in[0];
  const float* x2    = (const float*)d_in[1];
  const float* w_fe  = (const float*)d_in[2];
  const float* gamma = (const float*)d_in[3];
  const float* beta  = (const float*)d_in[4];
  const float* mean  = (const float*)d_in[5];
  const float* var   = (const float*)d_in[6];
  const float* w_cg1 = (const float*)d_in[7];
  const float* w_cg2 = (const float*)d_in[8];
  const float* w_ag1 = (const float*)d_in[9];
  const float* w_ag2 = (const float*)d_in[10];
  float* out = (float*)d_out;

  // workspace layout (~470 KB)
  char* ws = (char*)d_ws;
  u32* Wp          = (u32*)(ws);                           // [0, 131072)
  float* scale     = (float*)(ws + 131072);                // 1 KB
  float* shift     = (float*)(ws + 132096);                // 1 KB
  float* pool_part = (float*)(ws + 133120);                // 256*256*4 = 256 KB
  float* cw        = (float*)(ws + 395264);                // 73728 B
  float* coef      = (float*)(ws + 468992);                // 64 B

  k0_prep<<<128, 256, 0, stream>>>(w_fe, gamma, beta, mean, var, Wp, scale, shift);
  k1_gemm_pool<<<256, 1024, 0, stream>>>(x1, x2, Wp, scale, shift, pool_part);
  k2_small<<<80, 256, 0, stream>>>(pool_part, w_cg1, w_cg2, w_ag1, w_ag2, cw, coef);
  k3_dynconv<<<8192, 256, 0, stream>>>(x1, x2, cw, coef, out);
}